// Round 8
// baseline (2108.286 us; speedup 1.0000x reference)
//
#include <hip/hip_runtime.h>

#define SEQ    2048
#define BATCH  16
#define HID    1024
#define M_TOT  (SEQ*BATCH)      // 32768 rows
#define NCH    (BATCH*HID)      // 16384 scan channels
#define NCHUNK 32
#define TCHUNK (SEQ/NCHUNK)     // 64 timesteps per chunk
#define NSEG   256              // 8-timestep segments (one per bm tile)

typedef __attribute__((ext_vector_type(8))) short          short8;
typedef __attribute__((ext_vector_type(8))) unsigned short ushort8_t;
typedef __attribute__((ext_vector_type(4))) float          floatx4;

__device__ __forceinline__ unsigned short f32_to_bf16(float f) {
  unsigned int u = __float_as_uint(f);
  u += 0x7FFFu + ((u >> 16) & 1u);           // round-to-nearest-even
  return (unsigned short)(u >> 16);
}
__device__ __forceinline__ float bf16_to_f32(unsigned short h) {
  return __uint_as_float(((unsigned int)h) << 16);
}
__device__ __forceinline__ float sigmoidf_(float x) {
  return 1.f / (1.f + __expf(-x));
}

// ============================================================================
// Swizzled operand layout ("fragment image"):
//   (R rows, K cols) bf16 -> blocks of 128 rows x 32 k = 4096 ushorts.
//   block = (row>>7)*(K/32) + (k>>5).  Within a block, for (r=row&127, kk=k&31):
//     unit = (r>>4)*64 + ((kk>>3)<<4) + (r&15);  ushort off = unit*8 + (kk&7)
//   MFMA fragment for rows j*16..j*16+15 = 1 KB at off j*512; lane l's 16B at
//   j*512 + l*8 -> direct global_load_dwordx4, fully coalesced.
// ============================================================================

// ---------------- prep bodies (fused into one launch) -----------------------
__device__ __forceinline__ void cast_swizzle_body(const float* __restrict__ src,
    unsigned short* __restrict__ dst, int mt, int kt, int t) {
  __shared__ unsigned short tile[4096];
  const int r = t >> 1, kh = (t & 1) * 16;
  const float* sp = src + (size_t)(mt * 128 + r) * 1024 + kt * 32 + kh;
  float4 v0 = *(const float4*)(sp + 0);
  float4 v1 = *(const float4*)(sp + 4);
  float4 v2 = *(const float4*)(sp + 8);
  float4 v3 = *(const float4*)(sp + 12);
  ushort8_t u0, u1;
  u0[0]=f32_to_bf16(v0.x); u0[1]=f32_to_bf16(v0.y); u0[2]=f32_to_bf16(v0.z); u0[3]=f32_to_bf16(v0.w);
  u0[4]=f32_to_bf16(v1.x); u0[5]=f32_to_bf16(v1.y); u0[6]=f32_to_bf16(v1.z); u0[7]=f32_to_bf16(v1.w);
  u1[0]=f32_to_bf16(v2.x); u1[1]=f32_to_bf16(v2.y); u1[2]=f32_to_bf16(v2.z); u1[3]=f32_to_bf16(v2.w);
  u1[4]=f32_to_bf16(v3.x); u1[5]=f32_to_bf16(v3.y); u1[6]=f32_to_bf16(v3.z); u1[7]=f32_to_bf16(v3.w);
  const int c = r >> 4, lr = r & 15, q0 = kh >> 3;
  const int unit0 = c * 64 + (q0 << 4) + lr;
  *(ushort8_t*)&tile[unit0 * 8]        = u0;
  *(ushort8_t*)&tile[(unit0 + 16) * 8] = u1;
  __syncthreads();
  const size_t base = ((size_t)mt * 32 + kt) * 4096;
  *(ushort8_t*)&dst[base + t * 16]     = *(const ushort8_t*)&tile[t * 16];
  *(ushort8_t*)&dst[base + t * 16 + 8] = *(const ushort8_t*)&tile[t * 16 + 8];
}

__device__ __forceinline__ void w_prep_body(const float* __restrict__ W,
    unsigned short* __restrict__ Wsw, int nt, int kt, int t) {
  __shared__ unsigned short tile[4096];
  const int kk = t >> 3, n0 = (t & 7) * 16;
  const float* sp = W + (size_t)(kt * 32 + kk) * 3072 + nt * 128 + n0;
  float v[16];
#pragma unroll
  for (int i = 0; i < 16; i += 4) {
    float4 f = *(const float4*)(sp + i);
    v[i] = f.x; v[i+1] = f.y; v[i+2] = f.z; v[i+3] = f.w;
  }
  const int cbase = (n0 >> 4) * 64 + ((kk >> 3) << 4);
#pragma unroll
  for (int j = 0; j < 16; j++)
    tile[(cbase + j) * 8 + (kk & 7)] = f32_to_bf16(v[j]);
  __syncthreads();
  const size_t base = ((size_t)nt * 32 + kt) * 4096;
  *(ushort8_t*)&Wsw[base + t * 16]     = *(const ushort8_t*)&tile[t * 16];
  *(ushort8_t*)&Wsw[base + t * 16 + 8] = *(const ushort8_t*)&tile[t * 16 + 8];
}

// one launch: blocks [0,8192) cast x; [8192,8960) W0; [8960,9728) W1
__global__ __launch_bounds__(256) void prep_all(const float* __restrict__ x,
    const float* __restrict__ W0, const float* __restrict__ W1,
    unsigned short* __restrict__ xsw, unsigned short* __restrict__ W0sw,
    unsigned short* __restrict__ W1sw) {
  const int id = blockIdx.x, t = threadIdx.x;
  if (id < 8192)        cast_swizzle_body(x, xsw, id >> 5, id & 31, t);
  else if (id < 8960)   w_prep_body(W0, W0sw, (id - 8192) >> 5, (id - 8192) & 31, t);
  else                  w_prep_body(W1, W1sw, (id - 8960) >> 5, (id - 8960) & 31, t);
}

// -------------------------------------------------- direct-load MFMA GEMM (layer 1)
// Block tile 128x256, 4 waves, wave tile 64x128 (4x8 acc).  No LDS, no
// barriers; register ping-pong over K.  116 VGPR, LDS=0 -> 3 blocks/CU.
// Region (block-uniform, BN=256): bn>>2 = 0:Xt 1:F 2:R.
__global__ __launch_bounds__(256, 3) void gemm_direct(
    const unsigned short* __restrict__ A, const unsigned short* __restrict__ B,
    unsigned short* __restrict__ Xt, unsigned short* __restrict__ Fo, unsigned short* __restrict__ Ro,
    const float* __restrict__ bias, int NBN2)
{
  const int tid = threadIdx.x;
  const int wave = tid >> 6, lane = tid & 63;
  const int wm = wave & 1, wn = wave >> 1;
  const int id = blockIdx.x;
  const int xcd = id & 7, slot = id >> 3;
  const int NB8 = NBN2 << 3;
  const int g = slot / NB8, rem = slot - g * NB8;
  const int bn = rem >> 3;
  const int bm = xcd * 32 + g * 8 + (rem & 7);

  const unsigned short* gA = A + (size_t)bm * 32 * 4096 + wm * 2048 + lane * 8;
  const unsigned short* gB = B + ((size_t)(bn * 2 + wn)) * 32 * 4096 + lane * 8;

  floatx4 acc[4][8];
#pragma unroll
  for (int i = 0; i < 4; i++)
#pragma unroll
    for (int j = 0; j < 8; j++)
#pragma unroll
      for (int r = 0; r < 4; r++) acc[i][j][r] = 0.f;

  short8 a0[4], b0[8], a1[4], b1[8];
  auto loadA = [&](short8* d, const unsigned short* p) {
#pragma unroll
    for (int i = 0; i < 4; i++) d[i] = *(const short8*)(p + i * 512);
  };
  auto loadB = [&](short8* d, const unsigned short* p) {
#pragma unroll
    for (int j = 0; j < 8; j++) d[j] = *(const short8*)(p + j * 512);
  };
  auto domfma = [&](short8* a, short8* b) {
#pragma unroll
    for (int i = 0; i < 4; i++)
#pragma unroll
      for (int j = 0; j < 8; j++)
        acc[i][j] = __builtin_amdgcn_mfma_f32_16x16x32_bf16(a[i], b[j], acc[i][j], 0, 0, 0);
  };

  loadA(a0, gA); loadB(b0, gB);
#pragma unroll 1
  for (int kt = 0; kt < 32; kt += 2) {
    loadA(a1, gA + 4096); loadB(b1, gB + 4096);   // prefetch kt+1
    domfma(a0, b0);
    gA += 8192; gB += 8192;
    if (kt + 2 < 32) { loadA(a0, gA); loadB(b0, gB); }  // prefetch kt+2
    domfma(a1, b1);
  }

  // epilogue: C/D layout col=lane&15, row=(lane>>4)*4+reg  [m89/m91-verified]
  const int region = bn >> 2;
  const int lc = (bn & 3) * 256 + wn * 128 + (lane & 15);
  const int row0 = bm * 128 + wm * 64 + ((lane >> 4) << 2);
  if (region == 0) {
#pragma unroll
    for (int i = 0; i < 4; i++)
#pragma unroll
      for (int j = 0; j < 8; j++)
#pragma unroll
        for (int rg = 0; rg < 4; rg++)
          Xt[(size_t)(row0 + i * 16 + rg) * 1024 + lc + j * 16] = f32_to_bf16(acc[i][j][rg]);
  } else {
    unsigned short* O = (region == 1) ? Fo : Ro;
    const float* bp = bias + (region - 1) * 1024;
#pragma unroll
    for (int j = 0; j < 8; j++) {
      float bb = bp[lc + j * 16];
#pragma unroll
      for (int i = 0; i < 4; i++)
#pragma unroll
        for (int rg = 0; rg < 4; rg++) {
          float s = sigmoidf_(acc[i][j][rg] + bb);
          O[(size_t)(row0 + i * 16 + rg) * 1024 + lc + j * 16] = f32_to_bf16(s);
        }
    }
  }
}

// ------------------- layer-2 GEMM with fused segment scan -------------------
// Block = (bm 0..255, bn 0..7): computes u_x = h1 @ W1[:, h-range] and
// u_f for the SAME h-range (paired column blocks), then runs the 8-step
// scan segment (t = bm*8 .. bm*8+7) in the epilogue and writes only
// (Pseg, Sseg).  No Xt/F materialization for layer 2 at all.
// Wave tile 64x64 per region: wm = rows, wn = col-half.
__global__ __launch_bounds__(256, 2) void gemm2_scan(
    const unsigned short* __restrict__ A, const unsigned short* __restrict__ B,
    const float* __restrict__ bias, float* __restrict__ Pseg, float* __restrict__ Sseg)
{
  __shared__ float lps[2][64][4][4][2];     // [wn][lane][rg][j][{p,s}] = 16 KB
  const int tid = threadIdx.x;
  const int wave = tid >> 6, lane = tid & 63;
  const int wm = wave & 1, wn = wave >> 1;
  const int id = blockIdx.x;
  const int xcd = id & 7, slot = id >> 3;          // 256 slots per xcd
  const int g = slot >> 6, rem = slot & 63;        // groups of 8 bm x 8 bn
  const int bn = rem >> 3;
  const int bm = xcd * 32 + g * 8 + (rem & 7);

  const unsigned short* gA  = A + (size_t)bm * 32 * 4096 + wm * 2048 + lane * 8;
  const unsigned short* gBx = B + (size_t)bn * 32 * 4096 + wn * 2048 + lane * 8;
  const unsigned short* gBf = B + (size_t)(8 + bn) * 32 * 4096 + wn * 2048 + lane * 8;

  floatx4 ax[4][4], af[4][4];
#pragma unroll
  for (int i = 0; i < 4; i++)
#pragma unroll
    for (int j = 0; j < 4; j++)
#pragma unroll
      for (int r = 0; r < 4; r++) { ax[i][j][r] = 0.f; af[i][j][r] = 0.f; }

  short8 a0[4], bx0[4], bf0[4], a1[4], bx1[4], bf1[4];
  auto load4 = [&](short8* d, const unsigned short* p) {
#pragma unroll
    for (int i = 0; i < 4; i++) d[i] = *(const short8*)(p + i * 512);
  };
  auto domfma = [&](short8* a, short8* bx, short8* bf) {
#pragma unroll
    for (int i = 0; i < 4; i++)
#pragma unroll
      for (int j = 0; j < 4; j++) {
        ax[i][j] = __builtin_amdgcn_mfma_f32_16x16x32_bf16(a[i], bx[j], ax[i][j], 0, 0, 0);
        af[i][j] = __builtin_amdgcn_mfma_f32_16x16x32_bf16(a[i], bf[j], af[i][j], 0, 0, 0);
      }
  };

  load4(a0, gA); load4(bx0, gBx); load4(bf0, gBf);
#pragma unroll 1
  for (int kt = 0; kt < 32; kt += 2) {
    load4(a1, gA + 4096); load4(bx1, gBx + 4096); load4(bf1, gBf + 4096);
    domfma(a0, bx0, bf0);
    gA += 8192; gBx += 8192; gBf += 8192;
    if (kt + 2 < 32) { load4(a0, gA); load4(bx0, gBx); load4(bf0, gBf); }
    domfma(a1, bx1, bf1);
  }

  // epilogue: per (j,rg): b = (lane>>4)*4+rg, h = bn*128+wn*64+j*16+(lane&15),
  // t = bm*8 + wm*4 + i.  4-step scan over i, cross-wm combine via LDS.
  const int q = lane >> 4, cc = lane & 15;
  float pv[4][4], sv[4][4];                 // [j][rg]
#pragma unroll
  for (int j = 0; j < 4; j++) {
    float bb = bias[bn * 128 + wn * 64 + j * 16 + cc];
#pragma unroll
    for (int rg = 0; rg < 4; rg++) {
      float p = 1.f, s = 0.f;
#pragma unroll
      for (int i = 0; i < 4; i++) {
        float f  = sigmoidf_(af[i][j][rg] + bb);
        float xt = ax[i][j][rg];
        s = f * s + (1.f - f) * xt;
        p *= f;
      }
      pv[j][rg] = p; sv[j][rg] = s;
    }
  }
  if (wm == 0) {
#pragma unroll
    for (int j = 0; j < 4; j++)
#pragma unroll
      for (int rg = 0; rg < 4; rg++) {
        lps[wn][lane][rg][j][0] = pv[j][rg];
        lps[wn][lane][rg][j][1] = sv[j][rg];
      }
  }
  __syncthreads();
  if (wm == 1) {
#pragma unroll
    for (int j = 0; j < 4; j++) {
      const int h = bn * 128 + wn * 64 + j * 16 + cc;
#pragma unroll
      for (int rg = 0; rg < 4; rg++) {
        float plo = lps[wn][lane][rg][j][0];
        float slo = lps[wn][lane][rg][j][1];
        float phi = pv[j][rg], shi = sv[j][rg];
        const size_t off = (size_t)bm * NCH + (q * 4 + rg) * 1024 + h;
        Pseg[off] = plo * phi;
        Sseg[off] = phi * slo + shi;
      }
    }
  }
}

// ---------------- blocked scan pass 1 (layer 1), 8 channels/thread ----------
__global__ __launch_bounds__(256) void scan_pass1(
    const unsigned short* __restrict__ Xt, const unsigned short* __restrict__ F,
    float* __restrict__ P, float* __restrict__ S) {
  const int ch = (blockIdx.x * 256 + threadIdx.x) * 8;
  const int chunk = blockIdx.y;
  size_t idx = (size_t)chunk * TCHUNK * NCH + ch;
  float p[8], s[8];
#pragma unroll
  for (int j = 0; j < 8; j++) { p[j] = 1.f; s[j] = 0.f; }
  for (int t = 0; t < TCHUNK; ++t) {
    ushort8_t fv = *(const ushort8_t*)&F[idx];
    ushort8_t xv = *(const ushort8_t*)&Xt[idx];
#pragma unroll
    for (int j = 0; j < 8; j++) {
      float f  = bf16_to_f32(fv[j]);
      float xt = bf16_to_f32(xv[j]);
      s[j] = f * s[j] + (1.f - f) * xt;
      p[j] *= f;
    }
    idx += NCH;
  }
  float4* P4 = (float4*)&P[(size_t)chunk * NCH + ch];
  float4* S4 = (float4*)&S[(size_t)chunk * NCH + ch];
  P4[0] = make_float4(p[0], p[1], p[2], p[3]);
  P4[1] = make_float4(p[4], p[5], p[6], p[7]);
  S4[0] = make_float4(s[0], s[1], s[2], s[3]);
  S4[1] = make_float4(s[4], s[5], s[6], s[7]);
}

// ---------------- serial combine -> carries (layer 1), 8 ch/thread ----------
__global__ __launch_bounds__(256) void combine_c0(
    const float* __restrict__ P, const float* __restrict__ S, float* __restrict__ C0) {
  const int ch = (blockIdx.x * 256 + threadIdx.x) * 8;
  float c[8];
#pragma unroll
  for (int j = 0; j < 8; j++) c[j] = 0.f;
  for (int k = 0; k < NCHUNK; ++k) {
    float4* O4 = (float4*)&C0[(size_t)k * NCH + ch];
    O4[0] = make_float4(c[0], c[1], c[2], c[3]);
    O4[1] = make_float4(c[4], c[5], c[6], c[7]);
    const float4* P4 = (const float4*)&P[(size_t)k * NCH + ch];
    const float4* S4 = (const float4*)&S[(size_t)k * NCH + ch];
    float4 p0 = P4[0], p1 = P4[1], s0 = S4[0], s1 = S4[1];
    c[0] = p0.x*c[0]+s0.x; c[1] = p0.y*c[1]+s0.y; c[2] = p0.z*c[2]+s0.z; c[3] = p0.w*c[3]+s0.w;
    c[4] = p1.x*c[4]+s1.x; c[5] = p1.y*c[5]+s1.y; c[6] = p1.z*c[6]+s1.z; c[7] = p1.w*c[7]+s1.w;
  }
}

// ------- pass 2 (layer 1): h1 = r*c + (1-r)*x, written DIRECTLY swizzled ----
// IN-PLACE: h1 overwrites xsw.  Block = (h-slab 128, chunk), 16b x 16hg.
#define TPAD 4112
__global__ __launch_bounds__(256) void scan1_pass2_fused(
    const unsigned short* __restrict__ Xt, const unsigned short* __restrict__ F,
    const unsigned short* __restrict__ R, unsigned short* __restrict__ xsw,
    const float* __restrict__ C0, unsigned short* __restrict__ h1last)
{
  __shared__ unsigned short st[4 * TPAD];
  const int hb = blockIdx.x;
  const int chunk = blockIdx.y;
  const int tid = threadIdx.x;
  const int b = tid >> 4, hg = tid & 15;
  const int h0 = hb * 128 + hg * 8;
  const int ch = b * 1024 + h0;
  const int tl   = hg >> 2;
  const int usub = (hg & 3) * 16 + b;

  float c[8];
  {
    const float4* C4 = (const float4*)&C0[(size_t)chunk * NCH + ch];
    float4 a = C4[0], d = C4[1];
    c[0]=a.x; c[1]=a.y; c[2]=a.z; c[3]=a.w; c[4]=d.x; c[5]=d.y; c[6]=d.z; c[7]=d.w;
  }

  size_t idx = (size_t)chunk * TCHUNK * NCH + ch;
  for (int t8 = 0; t8 < 8; ++t8) {
#pragma unroll
    for (int ts = 0; ts < 8; ++ts) {
      const int t = chunk * TCHUNK + t8 * 8 + ts;
      ushort8_t fv = *(const ushort8_t*)&F[idx];
      ushort8_t xv = *(const ushort8_t*)&Xt[idx];
      ushort8_t rv = *(const ushort8_t*)&R[idx];
      const size_t soff = ((size_t)(t >> 3) * 32 + (h0 >> 5)) * 4096
                        + (size_t)(((t & 7) * 64 + usub) * 8);
      ushort8_t xo = *(const ushort8_t*)&xsw[soff];
      ushort8_t hv;
#pragma unroll
      for (int j = 0; j < 8; ++j) {
        float f  = bf16_to_f32(fv[j]);
        float xt = bf16_to_f32(xv[j]);
        c[j] = f * c[j] + (1.f - f) * xt;
        float r  = bf16_to_f32(rv[j]);
        float xval = bf16_to_f32(xo[j]);
        hv[j] = f32_to_bf16(r * c[j] + (1.f - r) * xval);
      }
      *(ushort8_t*)&st[tl * TPAD + (ts * 64 + usub) * 8] = hv;
      if (t == SEQ - 1) *(ushort8_t*)&h1last[ch] = hv;
      idx += NCH;
    }
    __syncthreads();
    const size_t gbase = (((size_t)chunk * 8 + t8) * 32 + hb * 4) * 4096;
#pragma unroll
    for (int tl2 = 0; tl2 < 4; ++tl2) {
      size_t gdst = gbase + (size_t)tl2 * 4096 + tid * 16;
      *(ushort8_t*)&xsw[gdst]     = *(const ushort8_t*)&st[tl2 * TPAD + tid * 16];
      *(ushort8_t*)&xsw[gdst + 8] = *(const ushort8_t*)&st[tl2 * TPAD + tid * 16 + 8];
    }
    __syncthreads();
  }
}

// ------- r2 at last timestep: (16x1024) @ W1[:,2048:3072] fp32, 64 blocks ---
__global__ __launch_bounds__(256) void r2_kernel(
    const unsigned short* __restrict__ h1last, const float* __restrict__ W1,
    const float* __restrict__ b1, float* __restrict__ r2) {
  __shared__ float xrow[1024];
  const int b = blockIdx.x, nq = blockIdx.y, tid = threadIdx.x;
  for (int i = tid; i < 1024; i += 256)
    xrow[i] = bf16_to_f32(h1last[b * 1024 + i]);
  __syncthreads();
  const int n = nq * 256 + tid;
  float acc = b1[1024 + n];
  for (int d = 0; d < 1024; ++d)
    acc += xrow[d] * W1[(size_t)d * 3072 + 2048 + n];
  r2[b * 1024 + n] = sigmoidf_(acc);
}

// ------- layer-2: 256-segment serial combine + final output -----------------
__global__ __launch_bounds__(256) void final_l2(
    const float* __restrict__ Pseg, const float* __restrict__ Sseg,
    const float* __restrict__ r2, const unsigned short* __restrict__ h1last,
    float* __restrict__ out) {
  const int ch = (blockIdx.x * 256 + threadIdx.x) * 8;
  float c[8];
#pragma unroll
  for (int j = 0; j < 8; j++) c[j] = 0.f;
#pragma unroll 4
  for (int k = 0; k < NSEG; ++k) {
    const float4* P4 = (const float4*)&Pseg[(size_t)k * NCH + ch];
    const float4* S4 = (const float4*)&Sseg[(size_t)k * NCH + ch];
    float4 p0 = P4[0], p1 = P4[1], s0 = S4[0], s1 = S4[1];
    c[0] = p0.x*c[0]+s0.x; c[1] = p0.y*c[1]+s0.y; c[2] = p0.z*c[2]+s0.z; c[3] = p0.w*c[3]+s0.w;
    c[4] = p1.x*c[4]+s1.x; c[5] = p1.y*c[5]+s1.y; c[6] = p1.z*c[6]+s1.z; c[7] = p1.w*c[7]+s1.w;
  }
  const float4* R4 = (const float4*)&r2[ch];
  float4 r0 = R4[0], r1 = R4[1];
  ushort8_t hx = *(const ushort8_t*)&h1last[ch];
  float rr[8] = {r0.x, r0.y, r0.z, r0.w, r1.x, r1.y, r1.z, r1.w};
  float o[8];
#pragma unroll
  for (int j = 0; j < 8; j++)
    o[j] = rr[j] * c[j] + (1.f - rr[j]) * bf16_to_f32(hx[j]);
  float4* O4 = (float4*)&out[ch];
  O4[0] = make_float4(o[0], o[1], o[2], o[3]);
  O4[1] = make_float4(o[4], o[5], o[6], o[7]);
}

extern "C" void kernel_launch(void* const* d_in, const int* in_sizes, int n_in,
                              void* d_out, int out_size, void* d_ws, size_t ws_size,
                              hipStream_t stream) {
  const float* x  = (const float*)d_in[0];
  const float* W0 = (const float*)d_in[1];
  const float* b0 = (const float*)d_in[2];
  const float* W1 = (const float*)d_in[3];
  const float* b1 = (const float*)d_in[4];
  float* out = (float*)d_out;

  char* ws = (char*)d_ws;
  auto alloc = [&](size_t bytes) {
    char* p = ws; ws += (bytes + 255) & ~(size_t)255; return p;
  };
  const size_t NE = (size_t)M_TOT * HID;
  unsigned short* xsw   = (unsigned short*)alloc(NE * 2);   // x swizzled; h1 in-place
  unsigned short* W0sw  = (unsigned short*)alloc((size_t)3072 * 1024 * 2);
  unsigned short* W1sw  = (unsigned short*)alloc((size_t)3072 * 1024 * 2);
  unsigned short* Xt    = (unsigned short*)alloc(NE * 2);
  unsigned short* F     = (unsigned short*)alloc(NE * 2);
  unsigned short* R     = (unsigned short*)alloc(NE * 2);
  unsigned short* h1last= (unsigned short*)alloc((size_t)NCH * 2);
  float* P    = (float*)alloc((size_t)NCHUNK * NCH * 4);
  float* S    = (float*)alloc((size_t)NCHUNK * NCH * 4);
  float* C0   = (float*)alloc((size_t)NCHUNK * NCH * 4);
  float* Pseg = (float*)alloc((size_t)NSEG * NCH * 4);      // 16.8 MB
  float* Sseg = (float*)alloc((size_t)NSEG * NCH * 4);
  float* r2   = (float*)alloc((size_t)NCH * 4);

  dim3 blk256(256);
  // 1. preprocessing: x->xsw, W0->W0sw, W1->W1sw
  prep_all<<<dim3(9728), blk256, 0, stream>>>(x, W0, W1, xsw, W0sw, W1sw);
  // 2. layer-1 GEMM (N=3072, BN=256 -> 12 bn blocks), direct-load, 3 blocks/CU
  gemm_direct<<<dim3(256 * 12), blk256, 0, stream>>>(xsw, W0sw, Xt, F, R, b0, 12);
  // 3. blocked scan layer 1
  scan_pass1<<<dim3(8, NCHUNK), blk256, 0, stream>>>(Xt, F, P, S);
  combine_c0<<<dim3(8), blk256, 0, stream>>>(P, S, C0);
  scan1_pass2_fused<<<dim3(8, NCHUNK), blk256, 0, stream>>>(Xt, F, R, xsw, C0, h1last);
  // 4. r2 at last timestep (fp32 path, independent of gemm2)
  r2_kernel<<<dim3(16, 4), blk256, 0, stream>>>(h1last, W1, b1, r2);
  // 5. layer-2 GEMM with fused segment scan (writes only Pseg/Sseg)
  gemm2_scan<<<dim3(2048), blk256, 0, stream>>>(xsw, W1sw, b1, Pseg, Sseg);
  // 6. 256-segment combine + output
  final_l2<<<dim3(8), blk256, 0, stream>>>(Pseg, Sseg, r2, h1last, out);
}

// Round 9
// 827.578 us; speedup vs baseline: 2.5475x; 2.5475x over previous
//
#include <hip/hip_runtime.h>

#define SEQ    2048
#define BATCH  16
#define HID    1024
#define M_TOT  (SEQ*BATCH)      // 32768 rows
#define NCH    (BATCH*HID)      // 16384 scan channels
#define NCHUNK 32
#define TCHUNK (SEQ/NCHUNK)     // 64 timesteps per chunk
#define NSEG   256              // 8-timestep segments (one per bm tile)

typedef __attribute__((ext_vector_type(8))) short          short8;
typedef __attribute__((ext_vector_type(8))) unsigned short ushort8_t;
typedef __attribute__((ext_vector_type(4))) float          floatx4;

__device__ __forceinline__ unsigned short f32_to_bf16(float f) {
  unsigned int u = __float_as_uint(f);
  u += 0x7FFFu + ((u >> 16) & 1u);           // round-to-nearest-even
  return (unsigned short)(u >> 16);
}
__device__ __forceinline__ float bf16_to_f32(unsigned short h) {
  return __uint_as_float(((unsigned int)h) << 16);
}
__device__ __forceinline__ float sigmoidf_(float x) {
  return 1.f / (1.f + __expf(-x));
}

// ============================================================================
// Swizzled operand layout ("fragment image"):
//   (R rows, K cols) bf16 -> blocks of 128 rows x 32 k = 4096 ushorts.
//   block = (row>>7)*(K/32) + (k>>5).  Within a block, for (r=row&127, kk=k&31):
//     unit = (r>>4)*64 + ((kk>>3)<<4) + (r&15);  ushort off = unit*8 + (kk&7)
//   MFMA fragment for rows j*16..j*16+15 = 1 KB at off j*512; lane l's 16B at
//   j*512 + l*8 -> direct global_load_dwordx4, fully coalesced.
// ============================================================================

// ---------------- prep bodies (fused into one launch) -----------------------
__device__ __forceinline__ void cast_swizzle_body(const float* __restrict__ src,
    unsigned short* __restrict__ dst, int mt, int kt, int t) {
  __shared__ unsigned short tile[4096];
  const int r = t >> 1, kh = (t & 1) * 16;
  const float* sp = src + (size_t)(mt * 128 + r) * 1024 + kt * 32 + kh;
  float4 v0 = *(const float4*)(sp + 0);
  float4 v1 = *(const float4*)(sp + 4);
  float4 v2 = *(const float4*)(sp + 8);
  float4 v3 = *(const float4*)(sp + 12);
  ushort8_t u0, u1;
  u0[0]=f32_to_bf16(v0.x); u0[1]=f32_to_bf16(v0.y); u0[2]=f32_to_bf16(v0.z); u0[3]=f32_to_bf16(v0.w);
  u0[4]=f32_to_bf16(v1.x); u0[5]=f32_to_bf16(v1.y); u0[6]=f32_to_bf16(v1.z); u0[7]=f32_to_bf16(v1.w);
  u1[0]=f32_to_bf16(v2.x); u1[1]=f32_to_bf16(v2.y); u1[2]=f32_to_bf16(v2.z); u1[3]=f32_to_bf16(v2.w);
  u1[4]=f32_to_bf16(v3.x); u1[5]=f32_to_bf16(v3.y); u1[6]=f32_to_bf16(v3.z); u1[7]=f32_to_bf16(v3.w);
  const int c = r >> 4, lr = r & 15, q0 = kh >> 3;
  const int unit0 = c * 64 + (q0 << 4) + lr;
  *(ushort8_t*)&tile[unit0 * 8]        = u0;
  *(ushort8_t*)&tile[(unit0 + 16) * 8] = u1;
  __syncthreads();
  const size_t base = ((size_t)mt * 32 + kt) * 4096;
  *(ushort8_t*)&dst[base + t * 16]     = *(const ushort8_t*)&tile[t * 16];
  *(ushort8_t*)&dst[base + t * 16 + 8] = *(const ushort8_t*)&tile[t * 16 + 8];
}

__device__ __forceinline__ void w_prep_body(const float* __restrict__ W,
    unsigned short* __restrict__ Wsw, int nt, int kt, int t) {
  __shared__ unsigned short tile[4096];
  const int kk = t >> 3, n0 = (t & 7) * 16;
  const float* sp = W + (size_t)(kt * 32 + kk) * 3072 + nt * 128 + n0;
  float v[16];
#pragma unroll
  for (int i = 0; i < 16; i += 4) {
    float4 f = *(const float4*)(sp + i);
    v[i] = f.x; v[i+1] = f.y; v[i+2] = f.z; v[i+3] = f.w;
  }
  const int cbase = (n0 >> 4) * 64 + ((kk >> 3) << 4);
#pragma unroll
  for (int j = 0; j < 16; j++)
    tile[(cbase + j) * 8 + (kk & 7)] = f32_to_bf16(v[j]);
  __syncthreads();
  const size_t base = ((size_t)nt * 32 + kt) * 4096;
  *(ushort8_t*)&Wsw[base + t * 16]     = *(const ushort8_t*)&tile[t * 16];
  *(ushort8_t*)&Wsw[base + t * 16 + 8] = *(const ushort8_t*)&tile[t * 16 + 8];
}

// one launch: blocks [0,8192) cast x; [8192,8960) W0; [8960,9728) W1
__global__ __launch_bounds__(256) void prep_all(const float* __restrict__ x,
    const float* __restrict__ W0, const float* __restrict__ W1,
    unsigned short* __restrict__ xsw, unsigned short* __restrict__ W0sw,
    unsigned short* __restrict__ W1sw) {
  const int id = blockIdx.x, t = threadIdx.x;
  if (id < 8192)        cast_swizzle_body(x, xsw, id >> 5, id & 31, t);
  else if (id < 8960)   w_prep_body(W0, W0sw, (id - 8192) >> 5, (id - 8192) & 31, t);
  else                  w_prep_body(W1, W1sw, (id - 8960) >> 5, (id - 8960) & 31, t);
}

// -------------------------------------------------- direct-load MFMA GEMM (layer 1)
// Block tile 128x256, 4 waves, wave tile 64x128 (4x8 acc).  No LDS, no
// barriers; register ping-pong over K.  NOTE: (256,2) is mandatory — (256,3)
// spills the 128-reg accumulator tile to scratch (R8: 4.3 GB WRITE, 6.5x slower).
// Region (block-uniform, BN=256): bn>>2 = 0:Xt 1:F 2:R.
__global__ __launch_bounds__(256, 2) void gemm_direct(
    const unsigned short* __restrict__ A, const unsigned short* __restrict__ B,
    unsigned short* __restrict__ Xt, unsigned short* __restrict__ Fo, unsigned short* __restrict__ Ro,
    const float* __restrict__ bias, int NBN2)
{
  const int tid = threadIdx.x;
  const int wave = tid >> 6, lane = tid & 63;
  const int wm = wave & 1, wn = wave >> 1;
  const int id = blockIdx.x;
  const int xcd = id & 7, slot = id >> 3;
  const int NB8 = NBN2 << 3;
  const int g = slot / NB8, rem = slot - g * NB8;
  const int bn = rem >> 3;
  const int bm = xcd * 32 + g * 8 + (rem & 7);

  const unsigned short* gA = A + (size_t)bm * 32 * 4096 + wm * 2048 + lane * 8;
  const unsigned short* gB = B + ((size_t)(bn * 2 + wn)) * 32 * 4096 + lane * 8;

  floatx4 acc[4][8];
#pragma unroll
  for (int i = 0; i < 4; i++)
#pragma unroll
    for (int j = 0; j < 8; j++)
#pragma unroll
      for (int r = 0; r < 4; r++) acc[i][j][r] = 0.f;

  short8 a0[4], b0[8], a1[4], b1[8];
  auto loadA = [&](short8* d, const unsigned short* p) {
#pragma unroll
    for (int i = 0; i < 4; i++) d[i] = *(const short8*)(p + i * 512);
  };
  auto loadB = [&](short8* d, const unsigned short* p) {
#pragma unroll
    for (int j = 0; j < 8; j++) d[j] = *(const short8*)(p + j * 512);
  };
  auto domfma = [&](short8* a, short8* b) {
#pragma unroll
    for (int i = 0; i < 4; i++)
#pragma unroll
      for (int j = 0; j < 8; j++)
        acc[i][j] = __builtin_amdgcn_mfma_f32_16x16x32_bf16(a[i], b[j], acc[i][j], 0, 0, 0);
  };

  loadA(a0, gA); loadB(b0, gB);
#pragma unroll 1
  for (int kt = 0; kt < 32; kt += 2) {
    loadA(a1, gA + 4096); loadB(b1, gB + 4096);   // prefetch kt+1
    domfma(a0, b0);
    gA += 8192; gB += 8192;
    if (kt + 2 < 32) { loadA(a0, gA); loadB(b0, gB); }  // prefetch kt+2
    domfma(a1, b1);
  }

  // epilogue: C/D layout col=lane&15, row=(lane>>4)*4+reg  [m89/m91-verified]
  const int region = bn >> 2;
  const int lc = (bn & 3) * 256 + wn * 128 + (lane & 15);
  const int row0 = bm * 128 + wm * 64 + ((lane >> 4) << 2);
  if (region == 0) {
#pragma unroll
    for (int i = 0; i < 4; i++)
#pragma unroll
      for (int j = 0; j < 8; j++)
#pragma unroll
        for (int rg = 0; rg < 4; rg++)
          Xt[(size_t)(row0 + i * 16 + rg) * 1024 + lc + j * 16] = f32_to_bf16(acc[i][j][rg]);
  } else {
    unsigned short* O = (region == 1) ? Fo : Ro;
    const float* bp = bias + (region - 1) * 1024;
#pragma unroll
    for (int j = 0; j < 8; j++) {
      float bb = bp[lc + j * 16];
#pragma unroll
      for (int i = 0; i < 4; i++)
#pragma unroll
        for (int rg = 0; rg < 4; rg++) {
          float s = sigmoidf_(acc[i][j][rg] + bb);
          O[(size_t)(row0 + i * 16 + rg) * 1024 + lc + j * 16] = f32_to_bf16(s);
        }
    }
  }
}

// ------------------- layer-2 GEMM with fused segment scan -------------------
// Block = (bm 0..255, bn 0..7): computes u_x = h1 @ W1[:, h-range] and
// u_f for the SAME h-range (paired column blocks), runs the 8-step scan
// segment (t = bm*8 .. bm*8+7) in the epilogue, writes only (Pseg, Sseg).
// No Xt/F materialization for layer 2 at all.
__global__ __launch_bounds__(256, 2) void gemm2_scan(
    const unsigned short* __restrict__ A, const unsigned short* __restrict__ B,
    const float* __restrict__ bias, float* __restrict__ Pseg, float* __restrict__ Sseg)
{
  __shared__ float lps[2][64][4][4][2];     // [wn][lane][rg][j][{p,s}] = 16 KB
  const int tid = threadIdx.x;
  const int wave = tid >> 6, lane = tid & 63;
  const int wm = wave & 1, wn = wave >> 1;
  const int id = blockIdx.x;
  const int xcd = id & 7, slot = id >> 3;          // 256 slots per xcd
  const int g = slot >> 6, rem = slot & 63;        // groups of 8 bm x 8 bn
  const int bn = rem >> 3;
  const int bm = xcd * 32 + g * 8 + (rem & 7);

  const unsigned short* gA  = A + (size_t)bm * 32 * 4096 + wm * 2048 + lane * 8;
  const unsigned short* gBx = B + (size_t)bn * 32 * 4096 + wn * 2048 + lane * 8;
  const unsigned short* gBf = B + (size_t)(8 + bn) * 32 * 4096 + wn * 2048 + lane * 8;

  floatx4 ax[4][4], af[4][4];
#pragma unroll
  for (int i = 0; i < 4; i++)
#pragma unroll
    for (int j = 0; j < 4; j++)
#pragma unroll
      for (int r = 0; r < 4; r++) { ax[i][j][r] = 0.f; af[i][j][r] = 0.f; }

  short8 a0[4], bx0[4], bf0[4], a1[4], bx1[4], bf1[4];
  auto load4 = [&](short8* d, const unsigned short* p) {
#pragma unroll
    for (int i = 0; i < 4; i++) d[i] = *(const short8*)(p + i * 512);
  };
  auto domfma = [&](short8* a, short8* bx, short8* bf) {
#pragma unroll
    for (int i = 0; i < 4; i++)
#pragma unroll
      for (int j = 0; j < 4; j++) {
        ax[i][j] = __builtin_amdgcn_mfma_f32_16x16x32_bf16(a[i], bx[j], ax[i][j], 0, 0, 0);
        af[i][j] = __builtin_amdgcn_mfma_f32_16x16x32_bf16(a[i], bf[j], af[i][j], 0, 0, 0);
      }
  };

  load4(a0, gA); load4(bx0, gBx); load4(bf0, gBf);
#pragma unroll 1
  for (int kt = 0; kt < 32; kt += 2) {
    load4(a1, gA + 4096); load4(bx1, gBx + 4096); load4(bf1, gBf + 4096);
    domfma(a0, bx0, bf0);
    gA += 8192; gBx += 8192; gBf += 8192;
    if (kt + 2 < 32) { load4(a0, gA); load4(bx0, gBx); load4(bf0, gBf); }
    domfma(a1, bx1, bf1);
  }

  // epilogue: per (j,rg): b = (lane>>4)*4+rg, h = bn*128+wn*64+j*16+(lane&15),
  // t = bm*8 + wm*4 + i.  4-step scan over i, cross-wm combine via LDS.
  const int q = lane >> 4, cc = lane & 15;
  float pv[4][4], sv[4][4];                 // [j][rg]
#pragma unroll
  for (int j = 0; j < 4; j++) {
    float bb = bias[bn * 128 + wn * 64 + j * 16 + cc];
#pragma unroll
    for (int rg = 0; rg < 4; rg++) {
      float p = 1.f, s = 0.f;
#pragma unroll
      for (int i = 0; i < 4; i++) {
        float f  = sigmoidf_(af[i][j][rg] + bb);
        float xt = ax[i][j][rg];
        s = f * s + (1.f - f) * xt;
        p *= f;
      }
      pv[j][rg] = p; sv[j][rg] = s;
    }
  }
  if (wm == 0) {
#pragma unroll
    for (int j = 0; j < 4; j++)
#pragma unroll
      for (int rg = 0; rg < 4; rg++) {
        lps[wn][lane][rg][j][0] = pv[j][rg];
        lps[wn][lane][rg][j][1] = sv[j][rg];
      }
  }
  __syncthreads();
  if (wm == 1) {
#pragma unroll
    for (int j = 0; j < 4; j++) {
      const int h = bn * 128 + wn * 64 + j * 16 + cc;
#pragma unroll
      for (int rg = 0; rg < 4; rg++) {
        float plo = lps[wn][lane][rg][j][0];
        float slo = lps[wn][lane][rg][j][1];
        float phi = pv[j][rg], shi = sv[j][rg];
        const size_t off = (size_t)bm * NCH + (q * 4 + rg) * 1024 + h;
        Pseg[off] = plo * phi;
        Sseg[off] = phi * slo + shi;
      }
    }
  }
}

// ---------------- blocked scan pass 1 (layer 1), 8 channels/thread ----------
__global__ __launch_bounds__(256) void scan_pass1(
    const unsigned short* __restrict__ Xt, const unsigned short* __restrict__ F,
    float* __restrict__ P, float* __restrict__ S) {
  const int ch = (blockIdx.x * 256 + threadIdx.x) * 8;
  const int chunk = blockIdx.y;
  size_t idx = (size_t)chunk * TCHUNK * NCH + ch;
  float p[8], s[8];
#pragma unroll
  for (int j = 0; j < 8; j++) { p[j] = 1.f; s[j] = 0.f; }
  for (int t = 0; t < TCHUNK; ++t) {
    ushort8_t fv = *(const ushort8_t*)&F[idx];
    ushort8_t xv = *(const ushort8_t*)&Xt[idx];
#pragma unroll
    for (int j = 0; j < 8; j++) {
      float f  = bf16_to_f32(fv[j]);
      float xt = bf16_to_f32(xv[j]);
      s[j] = f * s[j] + (1.f - f) * xt;
      p[j] *= f;
    }
    idx += NCH;
  }
  float4* P4 = (float4*)&P[(size_t)chunk * NCH + ch];
  float4* S4 = (float4*)&S[(size_t)chunk * NCH + ch];
  P4[0] = make_float4(p[0], p[1], p[2], p[3]);
  P4[1] = make_float4(p[4], p[5], p[6], p[7]);
  S4[0] = make_float4(s[0], s[1], s[2], s[3]);
  S4[1] = make_float4(s[4], s[5], s[6], s[7]);
}

// ---------------- serial combine -> carries (layer 1), 8 ch/thread ----------
__global__ __launch_bounds__(256) void combine_c0(
    const float* __restrict__ P, const float* __restrict__ S, float* __restrict__ C0) {
  const int ch = (blockIdx.x * 256 + threadIdx.x) * 8;
  float c[8];
#pragma unroll
  for (int j = 0; j < 8; j++) c[j] = 0.f;
  for (int k = 0; k < NCHUNK; ++k) {
    float4* O4 = (float4*)&C0[(size_t)k * NCH + ch];
    O4[0] = make_float4(c[0], c[1], c[2], c[3]);
    O4[1] = make_float4(c[4], c[5], c[6], c[7]);
    const float4* P4 = (const float4*)&P[(size_t)k * NCH + ch];
    const float4* S4 = (const float4*)&S[(size_t)k * NCH + ch];
    float4 p0 = P4[0], p1 = P4[1], s0 = S4[0], s1 = S4[1];
    c[0] = p0.x*c[0]+s0.x; c[1] = p0.y*c[1]+s0.y; c[2] = p0.z*c[2]+s0.z; c[3] = p0.w*c[3]+s0.w;
    c[4] = p1.x*c[4]+s1.x; c[5] = p1.y*c[5]+s1.y; c[6] = p1.z*c[6]+s1.z; c[7] = p1.w*c[7]+s1.w;
  }
}

// ------- pass 2 (layer 1): h1 = r*c + (1-r)*x, written DIRECTLY swizzled ----
// IN-PLACE: h1 overwrites xsw.  Block = (h-slab 128, chunk), 16b x 16hg.
#define TPAD 4112
__global__ __launch_bounds__(256) void scan1_pass2_fused(
    const unsigned short* __restrict__ Xt, const unsigned short* __restrict__ F,
    const unsigned short* __restrict__ R, unsigned short* __restrict__ xsw,
    const float* __restrict__ C0, unsigned short* __restrict__ h1last)
{
  __shared__ unsigned short st[4 * TPAD];
  const int hb = blockIdx.x;
  const int chunk = blockIdx.y;
  const int tid = threadIdx.x;
  const int b = tid >> 4, hg = tid & 15;
  const int h0 = hb * 128 + hg * 8;
  const int ch = b * 1024 + h0;
  const int tl   = hg >> 2;
  const int usub = (hg & 3) * 16 + b;

  float c[8];
  {
    const float4* C4 = (const float4*)&C0[(size_t)chunk * NCH + ch];
    float4 a = C4[0], d = C4[1];
    c[0]=a.x; c[1]=a.y; c[2]=a.z; c[3]=a.w; c[4]=d.x; c[5]=d.y; c[6]=d.z; c[7]=d.w;
  }

  size_t idx = (size_t)chunk * TCHUNK * NCH + ch;
  for (int t8 = 0; t8 < 8; ++t8) {
#pragma unroll
    for (int ts = 0; ts < 8; ++ts) {
      const int t = chunk * TCHUNK + t8 * 8 + ts;
      ushort8_t fv = *(const ushort8_t*)&F[idx];
      ushort8_t xv = *(const ushort8_t*)&Xt[idx];
      ushort8_t rv = *(const ushort8_t*)&R[idx];
      const size_t soff = ((size_t)(t >> 3) * 32 + (h0 >> 5)) * 4096
                        + (size_t)(((t & 7) * 64 + usub) * 8);
      ushort8_t xo = *(const ushort8_t*)&xsw[soff];
      ushort8_t hv;
#pragma unroll
      for (int j = 0; j < 8; ++j) {
        float f  = bf16_to_f32(fv[j]);
        float xt = bf16_to_f32(xv[j]);
        c[j] = f * c[j] + (1.f - f) * xt;
        float r  = bf16_to_f32(rv[j]);
        float xval = bf16_to_f32(xo[j]);
        hv[j] = f32_to_bf16(r * c[j] + (1.f - r) * xval);
      }
      *(ushort8_t*)&st[tl * TPAD + (ts * 64 + usub) * 8] = hv;
      if (t == SEQ - 1) *(ushort8_t*)&h1last[ch] = hv;
      idx += NCH;
    }
    __syncthreads();
    const size_t gbase = (((size_t)chunk * 8 + t8) * 32 + hb * 4) * 4096;
#pragma unroll
    for (int tl2 = 0; tl2 < 4; ++tl2) {
      size_t gdst = gbase + (size_t)tl2 * 4096 + tid * 16;
      *(ushort8_t*)&xsw[gdst]     = *(const ushort8_t*)&st[tl2 * TPAD + tid * 16];
      *(ushort8_t*)&xsw[gdst + 8] = *(const ushort8_t*)&st[tl2 * TPAD + tid * 16 + 8];
    }
    __syncthreads();
  }
}

// ------- r2 at last timestep: (16x1024) @ W1[:,2048:3072] fp32, 64 blocks ---
__global__ __launch_bounds__(256) void r2_kernel(
    const unsigned short* __restrict__ h1last, const float* __restrict__ W1,
    const float* __restrict__ b1, float* __restrict__ r2) {
  __shared__ float xrow[1024];
  const int b = blockIdx.x, nq = blockIdx.y, tid = threadIdx.x;
  for (int i = tid; i < 1024; i += 256)
    xrow[i] = bf16_to_f32(h1last[b * 1024 + i]);
  __syncthreads();
  const int n = nq * 256 + tid;
  float acc = b1[1024 + n];
  for (int d = 0; d < 1024; ++d)
    acc += xrow[d] * W1[(size_t)d * 3072 + 2048 + n];
  r2[b * 1024 + n] = sigmoidf_(acc);
}

// ------- layer-2: 256-segment serial combine + final output -----------------
__global__ __launch_bounds__(256) void final_l2(
    const float* __restrict__ Pseg, const float* __restrict__ Sseg,
    const float* __restrict__ r2, const unsigned short* __restrict__ h1last,
    float* __restrict__ out) {
  const int ch = (blockIdx.x * 256 + threadIdx.x) * 8;
  float c[8];
#pragma unroll
  for (int j = 0; j < 8; j++) c[j] = 0.f;
#pragma unroll 4
  for (int k = 0; k < NSEG; ++k) {
    const float4* P4 = (const float4*)&Pseg[(size_t)k * NCH + ch];
    const float4* S4 = (const float4*)&Sseg[(size_t)k * NCH + ch];
    float4 p0 = P4[0], p1 = P4[1], s0 = S4[0], s1 = S4[1];
    c[0] = p0.x*c[0]+s0.x; c[1] = p0.y*c[1]+s0.y; c[2] = p0.z*c[2]+s0.z; c[3] = p0.w*c[3]+s0.w;
    c[4] = p1.x*c[4]+s1.x; c[5] = p1.y*c[5]+s1.y; c[6] = p1.z*c[6]+s1.z; c[7] = p1.w*c[7]+s1.w;
  }
  const float4* R4 = (const float4*)&r2[ch];
  float4 r0 = R4[0], r1 = R4[1];
  ushort8_t hx = *(const ushort8_t*)&h1last[ch];
  float rr[8] = {r0.x, r0.y, r0.z, r0.w, r1.x, r1.y, r1.z, r1.w};
  float o[8];
#pragma unroll
  for (int j = 0; j < 8; j++)
    o[j] = rr[j] * c[j] + (1.f - rr[j]) * bf16_to_f32(hx[j]);
  float4* O4 = (float4*)&out[ch];
  O4[0] = make_float4(o[0], o[1], o[2], o[3]);
  O4[1] = make_float4(o[4], o[5], o[6], o[7]);
}

extern "C" void kernel_launch(void* const* d_in, const int* in_sizes, int n_in,
                              void* d_out, int out_size, void* d_ws, size_t ws_size,
                              hipStream_t stream) {
  const float* x  = (const float*)d_in[0];
  const float* W0 = (const float*)d_in[1];
  const float* b0 = (const float*)d_in[2];
  const float* W1 = (const float*)d_in[3];
  const float* b1 = (const float*)d_in[4];
  float* out = (float*)d_out;

  char* ws = (char*)d_ws;
  auto alloc = [&](size_t bytes) {
    char* p = ws; ws += (bytes + 255) & ~(size_t)255; return p;
  };
  const size_t NE = (size_t)M_TOT * HID;
  unsigned short* xsw   = (unsigned short*)alloc(NE * 2);   // x swizzled; h1 in-place
  unsigned short* W0sw  = (unsigned short*)alloc((size_t)3072 * 1024 * 2);
  unsigned short* W1sw  = (unsigned short*)alloc((size_t)3072 * 1024 * 2);
  unsigned short* Xt    = (unsigned short*)alloc(NE * 2);
  unsigned short* F     = (unsigned short*)alloc(NE * 2);
  unsigned short* R     = (unsigned short*)alloc(NE * 2);
  unsigned short* h1last= (unsigned short*)alloc((size_t)NCH * 2);
  float* P    = (float*)alloc((size_t)NCHUNK * NCH * 4);
  float* S    = (float*)alloc((size_t)NCHUNK * NCH * 4);
  float* C0   = (float*)alloc((size_t)NCHUNK * NCH * 4);
  float* Pseg = (float*)alloc((size_t)NSEG * NCH * 4);      // 16.8 MB
  float* Sseg = (float*)alloc((size_t)NSEG * NCH * 4);
  float* r2   = (float*)alloc((size_t)NCH * 4);

  dim3 blk256(256);
  // 1. preprocessing: x->xsw, W0->W0sw, W1->W1sw
  prep_all<<<dim3(9728), blk256, 0, stream>>>(x, W0, W1, xsw, W0sw, W1sw);
  // 2. layer-1 GEMM (N=3072, BN=256 -> 12 bn blocks), direct-load
  gemm_direct<<<dim3(256 * 12), blk256, 0, stream>>>(xsw, W0sw, Xt, F, R, b0, 12);
  // 3. blocked scan layer 1
  scan_pass1<<<dim3(8, NCHUNK), blk256, 0, stream>>>(Xt, F, P, S);
  combine_c0<<<dim3(8), blk256, 0, stream>>>(P, S, C0);
  scan1_pass2_fused<<<dim3(8, NCHUNK), blk256, 0, stream>>>(Xt, F, R, xsw, C0, h1last);
  // 4. r2 at last timestep (fp32 path, independent of gemm2)
  r2_kernel<<<dim3(16, 4), blk256, 0, stream>>>(h1last, W1, b1, r2);
  // 5. layer-2 GEMM with fused segment scan (writes only Pseg/Sseg)
  gemm2_scan<<<dim3(2048), blk256, 0, stream>>>(xsw, W1sw, b1, Pseg, Sseg);
  // 6. 256-segment combine + output
  final_l2<<<dim3(8), blk256, 0, stream>>>(Pseg, Sseg, r2, h1last, out);
}

// Round 10
// 759.677 us; speedup vs baseline: 2.7752x; 1.0894x over previous
//
#include <hip/hip_runtime.h>

#define SEQ    2048
#define BATCH  16
#define HID    1024
#define M_TOT  (SEQ*BATCH)      // 32768 rows
#define NCH    (BATCH*HID)      // 16384 scan channels
#define NCHUNK 64
#define TCHUNK (SEQ/NCHUNK)     // 32 timesteps per chunk
#define NSEG   256              // 8-timestep segments (one per bm tile)

typedef __attribute__((ext_vector_type(8))) short          short8;
typedef __attribute__((ext_vector_type(8))) unsigned short ushort8_t;
typedef __attribute__((ext_vector_type(4))) float          floatx4;

__device__ __forceinline__ unsigned short f32_to_bf16(float f) {
  unsigned int u = __float_as_uint(f);
  u += 0x7FFFu + ((u >> 16) & 1u);           // round-to-nearest-even
  return (unsigned short)(u >> 16);
}
__device__ __forceinline__ float bf16_to_f32(unsigned short h) {
  return __uint_as_float(((unsigned int)h) << 16);
}
__device__ __forceinline__ float sigmoidf_(float x) {
  return 1.f / (1.f + __expf(-x));
}

// ============================================================================
// Swizzled operand layout ("fragment image"):
//   (R rows, K cols) bf16 -> blocks of 128 rows x 32 k = 4096 ushorts.
//   block = (row>>7)*(K/32) + (k>>5).  Within a block, for (r=row&127, kk=k&31):
//     unit = (r>>4)*64 + ((kk>>3)<<4) + (r&15);  ushort off = unit*8 + (kk&7)
//   MFMA fragment for rows j*16..j*16+15 = 1 KB at off j*512; lane l's 16B at
//   j*512 + l*8 -> direct global_load_dwordx4, fully coalesced.
// ============================================================================

// ---------------- prep bodies (fused into one launch) -----------------------
__device__ __forceinline__ void cast_swizzle_body(const float* __restrict__ src,
    unsigned short* __restrict__ dst, int mt, int kt, int t) {
  __shared__ unsigned short tile[4096];
  const int r = t >> 1, kh = (t & 1) * 16;
  const float* sp = src + (size_t)(mt * 128 + r) * 1024 + kt * 32 + kh;
  float4 v0 = *(const float4*)(sp + 0);
  float4 v1 = *(const float4*)(sp + 4);
  float4 v2 = *(const float4*)(sp + 8);
  float4 v3 = *(const float4*)(sp + 12);
  ushort8_t u0, u1;
  u0[0]=f32_to_bf16(v0.x); u0[1]=f32_to_bf16(v0.y); u0[2]=f32_to_bf16(v0.z); u0[3]=f32_to_bf16(v0.w);
  u0[4]=f32_to_bf16(v1.x); u0[5]=f32_to_bf16(v1.y); u0[6]=f32_to_bf16(v1.z); u0[7]=f32_to_bf16(v1.w);
  u1[0]=f32_to_bf16(v2.x); u1[1]=f32_to_bf16(v2.y); u1[2]=f32_to_bf16(v2.z); u1[3]=f32_to_bf16(v2.w);
  u1[4]=f32_to_bf16(v3.x); u1[5]=f32_to_bf16(v3.y); u1[6]=f32_to_bf16(v3.z); u1[7]=f32_to_bf16(v3.w);
  const int c = r >> 4, lr = r & 15, q0 = kh >> 3;
  const int unit0 = c * 64 + (q0 << 4) + lr;
  *(ushort8_t*)&tile[unit0 * 8]        = u0;
  *(ushort8_t*)&tile[(unit0 + 16) * 8] = u1;
  __syncthreads();
  const size_t base = ((size_t)mt * 32 + kt) * 4096;
  *(ushort8_t*)&dst[base + t * 16]     = *(const ushort8_t*)&tile[t * 16];
  *(ushort8_t*)&dst[base + t * 16 + 8] = *(const ushort8_t*)&tile[t * 16 + 8];
}

__device__ __forceinline__ void w_prep_body(const float* __restrict__ W,
    unsigned short* __restrict__ Wsw, int nt, int kt, int t) {
  __shared__ unsigned short tile[4096];
  const int kk = t >> 3, n0 = (t & 7) * 16;
  const float* sp = W + (size_t)(kt * 32 + kk) * 3072 + nt * 128 + n0;
  float v[16];
#pragma unroll
  for (int i = 0; i < 16; i += 4) {
    float4 f = *(const float4*)(sp + i);
    v[i] = f.x; v[i+1] = f.y; v[i+2] = f.z; v[i+3] = f.w;
  }
  const int cbase = (n0 >> 4) * 64 + ((kk >> 3) << 4);
#pragma unroll
  for (int j = 0; j < 16; j++)
    tile[(cbase + j) * 8 + (kk & 7)] = f32_to_bf16(v[j]);
  __syncthreads();
  const size_t base = ((size_t)nt * 32 + kt) * 4096;
  *(ushort8_t*)&Wsw[base + t * 16]     = *(const ushort8_t*)&tile[t * 16];
  *(ushort8_t*)&Wsw[base + t * 16 + 8] = *(const ushort8_t*)&tile[t * 16 + 8];
}

// one launch: blocks [0,8192) cast x; [8192,8960) W0; [8960,9728) W1
__global__ __launch_bounds__(256) void prep_all(const float* __restrict__ x,
    const float* __restrict__ W0, const float* __restrict__ W1,
    unsigned short* __restrict__ xsw, unsigned short* __restrict__ W0sw,
    unsigned short* __restrict__ W1sw) {
  const int id = blockIdx.x, t = threadIdx.x;
  if (id < 8192)        cast_swizzle_body(x, xsw, id >> 5, id & 31, t);
  else if (id < 8960)   w_prep_body(W0, W0sw, (id - 8192) >> 5, (id - 8192) & 31, t);
  else                  w_prep_body(W1, W1sw, (id - 8960) >> 5, (id - 8960) & 31, t);
}

// -------------------------------------------------- direct-load MFMA GEMM (layer 1)
// Block tile 128x256, 4 waves, wave tile 64x128 (4x8 acc).  No LDS, no
// barriers; register ping-pong over K.  NOTE: (256,2) is mandatory — (256,3)
// spills the 128-reg accumulator tile to scratch (R8: 4.3 GB WRITE, 6.5x slower).
// Region (block-uniform, BN=256): bn>>2 = 0:Xt 1:F 2:R.
__global__ __launch_bounds__(256, 2) void gemm_direct(
    const unsigned short* __restrict__ A, const unsigned short* __restrict__ B,
    unsigned short* __restrict__ Xt, unsigned short* __restrict__ Fo, unsigned short* __restrict__ Ro,
    const float* __restrict__ bias, int NBN2)
{
  const int tid = threadIdx.x;
  const int wave = tid >> 6, lane = tid & 63;
  const int wm = wave & 1, wn = wave >> 1;
  const int id = blockIdx.x;
  const int xcd = id & 7, slot = id >> 3;
  const int NB8 = NBN2 << 3;
  const int g = slot / NB8, rem = slot - g * NB8;
  const int bn = rem >> 3;
  const int bm = xcd * 32 + g * 8 + (rem & 7);

  const unsigned short* gA = A + (size_t)bm * 32 * 4096 + wm * 2048 + lane * 8;
  const unsigned short* gB = B + ((size_t)(bn * 2 + wn)) * 32 * 4096 + lane * 8;

  floatx4 acc[4][8];
#pragma unroll
  for (int i = 0; i < 4; i++)
#pragma unroll
    for (int j = 0; j < 8; j++)
#pragma unroll
      for (int r = 0; r < 4; r++) acc[i][j][r] = 0.f;

  short8 a0[4], b0[8], a1[4], b1[8];
  auto loadA = [&](short8* d, const unsigned short* p) {
#pragma unroll
    for (int i = 0; i < 4; i++) d[i] = *(const short8*)(p + i * 512);
  };
  auto loadB = [&](short8* d, const unsigned short* p) {
#pragma unroll
    for (int j = 0; j < 8; j++) d[j] = *(const short8*)(p + j * 512);
  };
  auto domfma = [&](short8* a, short8* b) {
#pragma unroll
    for (int i = 0; i < 4; i++)
#pragma unroll
      for (int j = 0; j < 8; j++)
        acc[i][j] = __builtin_amdgcn_mfma_f32_16x16x32_bf16(a[i], b[j], acc[i][j], 0, 0, 0);
  };

  loadA(a0, gA); loadB(b0, gB);
#pragma unroll 1
  for (int kt = 0; kt < 32; kt += 2) {
    loadA(a1, gA + 4096); loadB(b1, gB + 4096);   // prefetch kt+1
    domfma(a0, b0);
    gA += 8192; gB += 8192;
    if (kt + 2 < 32) { loadA(a0, gA); loadB(b0, gB); }  // prefetch kt+2
    domfma(a1, b1);
  }

  // epilogue: C/D layout col=lane&15, row=(lane>>4)*4+reg  [m89/m91-verified]
  const int region = bn >> 2;
  const int lc = (bn & 3) * 256 + wn * 128 + (lane & 15);
  const int row0 = bm * 128 + wm * 64 + ((lane >> 4) << 2);
  if (region == 0) {
#pragma unroll
    for (int i = 0; i < 4; i++)
#pragma unroll
      for (int j = 0; j < 8; j++)
#pragma unroll
        for (int rg = 0; rg < 4; rg++)
          Xt[(size_t)(row0 + i * 16 + rg) * 1024 + lc + j * 16] = f32_to_bf16(acc[i][j][rg]);
  } else {
    unsigned short* O = (region == 1) ? Fo : Ro;
    const float* bp = bias + (region - 1) * 1024;
#pragma unroll
    for (int j = 0; j < 8; j++) {
      float bb = bp[lc + j * 16];
#pragma unroll
      for (int i = 0; i < 4; i++)
#pragma unroll
        for (int rg = 0; rg < 4; rg++) {
          float s = sigmoidf_(acc[i][j][rg] + bb);
          O[(size_t)(row0 + i * 16 + rg) * 1024 + lc + j * 16] = f32_to_bf16(s);
        }
    }
  }
}

// ------------------- layer-2 GEMM with fused segment scan -------------------
// Block = (bm 0..255, bn 0..7): computes u_x = h1 @ W1[:, h-range] and
// u_f for the SAME h-range (paired column blocks), runs the 8-step scan
// segment (t = bm*8 .. bm*8+7) in the epilogue, writes only (Pseg, Sseg).
__global__ __launch_bounds__(256, 2) void gemm2_scan(
    const unsigned short* __restrict__ A, const unsigned short* __restrict__ B,
    const float* __restrict__ bias, float* __restrict__ Pseg, float* __restrict__ Sseg)
{
  __shared__ float lps[2][64][4][4][2];     // [wn][lane][rg][j][{p,s}] = 16 KB
  const int tid = threadIdx.x;
  const int wave = tid >> 6, lane = tid & 63;
  const int wm = wave & 1, wn = wave >> 1;
  const int id = blockIdx.x;
  const int xcd = id & 7, slot = id >> 3;          // 256 slots per xcd
  const int g = slot >> 6, rem = slot & 63;        // groups of 8 bm x 8 bn
  const int bn = rem >> 3;
  const int bm = xcd * 32 + g * 8 + (rem & 7);

  const unsigned short* gA  = A + (size_t)bm * 32 * 4096 + wm * 2048 + lane * 8;
  const unsigned short* gBx = B + (size_t)bn * 32 * 4096 + wn * 2048 + lane * 8;
  const unsigned short* gBf = B + (size_t)(8 + bn) * 32 * 4096 + wn * 2048 + lane * 8;

  floatx4 ax[4][4], af[4][4];
#pragma unroll
  for (int i = 0; i < 4; i++)
#pragma unroll
    for (int j = 0; j < 4; j++)
#pragma unroll
      for (int r = 0; r < 4; r++) { ax[i][j][r] = 0.f; af[i][j][r] = 0.f; }

  short8 a0[4], bx0[4], bf0[4], a1[4], bx1[4], bf1[4];
  auto load4 = [&](short8* d, const unsigned short* p) {
#pragma unroll
    for (int i = 0; i < 4; i++) d[i] = *(const short8*)(p + i * 512);
  };
  auto domfma = [&](short8* a, short8* bx, short8* bf) {
#pragma unroll
    for (int i = 0; i < 4; i++)
#pragma unroll
      for (int j = 0; j < 4; j++) {
        ax[i][j] = __builtin_amdgcn_mfma_f32_16x16x32_bf16(a[i], bx[j], ax[i][j], 0, 0, 0);
        af[i][j] = __builtin_amdgcn_mfma_f32_16x16x32_bf16(a[i], bf[j], af[i][j], 0, 0, 0);
      }
  };

  load4(a0, gA); load4(bx0, gBx); load4(bf0, gBf);
#pragma unroll 1
  for (int kt = 0; kt < 32; kt += 2) {
    load4(a1, gA + 4096); load4(bx1, gBx + 4096); load4(bf1, gBf + 4096);
    domfma(a0, bx0, bf0);
    gA += 8192; gBx += 8192; gBf += 8192;
    if (kt + 2 < 32) { load4(a0, gA); load4(bx0, gBx); load4(bf0, gBf); }
    domfma(a1, bx1, bf1);
  }

  // epilogue: per (j,rg): b = (lane>>4)*4+rg, h = bn*128+wn*64+j*16+(lane&15),
  // t = bm*8 + wm*4 + i.  4-step scan over i, cross-wm combine via LDS.
  const int q = lane >> 4, cc = lane & 15;
  float pv[4][4], sv[4][4];                 // [j][rg]
#pragma unroll
  for (int j = 0; j < 4; j++) {
    float bb = bias[bn * 128 + wn * 64 + j * 16 + cc];
#pragma unroll
    for (int rg = 0; rg < 4; rg++) {
      float p = 1.f, s = 0.f;
#pragma unroll
      for (int i = 0; i < 4; i++) {
        float f  = sigmoidf_(af[i][j][rg] + bb);
        float xt = ax[i][j][rg];
        s = f * s + (1.f - f) * xt;
        p *= f;
      }
      pv[j][rg] = p; sv[j][rg] = s;
    }
  }
  if (wm == 0) {
#pragma unroll
    for (int j = 0; j < 4; j++)
#pragma unroll
      for (int rg = 0; rg < 4; rg++) {
        lps[wn][lane][rg][j][0] = pv[j][rg];
        lps[wn][lane][rg][j][1] = sv[j][rg];
      }
  }
  __syncthreads();
  if (wm == 1) {
#pragma unroll
    for (int j = 0; j < 4; j++) {
      const int h = bn * 128 + wn * 64 + j * 16 + cc;
#pragma unroll
      for (int rg = 0; rg < 4; rg++) {
        float plo = lps[wn][lane][rg][j][0];
        float slo = lps[wn][lane][rg][j][1];
        float phi = pv[j][rg], shi = sv[j][rg];
        const size_t off = (size_t)bm * NCH + (q * 4 + rg) * 1024 + h;
        Pseg[off] = plo * phi;
        Sseg[off] = phi * slo + shi;
      }
    }
  }
}

// ---------------- blocked scan pass 1 (layer 1), 8 channels/thread ----------
// 64 chunks of 32 timesteps -> 512 blocks (2/CU), serial depth 32.
__global__ __launch_bounds__(256) void scan_pass1(
    const unsigned short* __restrict__ Xt, const unsigned short* __restrict__ F,
    float* __restrict__ P, float* __restrict__ S) {
  const int ch = (blockIdx.x * 256 + threadIdx.x) * 8;
  const int chunk = blockIdx.y;
  size_t idx = (size_t)chunk * TCHUNK * NCH + ch;
  float p[8], s[8];
#pragma unroll
  for (int j = 0; j < 8; j++) { p[j] = 1.f; s[j] = 0.f; }
  for (int t = 0; t < TCHUNK; ++t) {
    ushort8_t fv = *(const ushort8_t*)&F[idx];
    ushort8_t xv = *(const ushort8_t*)&Xt[idx];
#pragma unroll
    for (int j = 0; j < 8; j++) {
      float f  = bf16_to_f32(fv[j]);
      float xt = bf16_to_f32(xv[j]);
      s[j] = f * s[j] + (1.f - f) * xt;
      p[j] *= f;
    }
    idx += NCH;
  }
  float4* P4 = (float4*)&P[(size_t)chunk * NCH + ch];
  float4* S4 = (float4*)&S[(size_t)chunk * NCH + ch];
  P4[0] = make_float4(p[0], p[1], p[2], p[3]);
  P4[1] = make_float4(p[4], p[5], p[6], p[7]);
  S4[0] = make_float4(s[0], s[1], s[2], s[3]);
  S4[1] = make_float4(s[4], s[5], s[6], s[7]);
}

// ---------------- serial combine -> carries (layer 1), 1 ch/thread ----------
// 64 blocks, fully coalesced 4 B accesses.
__global__ __launch_bounds__(256) void combine_c0(
    const float* __restrict__ P, const float* __restrict__ S, float* __restrict__ C0) {
  const int ch = blockIdx.x * 256 + threadIdx.x;
  float c = 0.f;
#pragma unroll 4
  for (int k = 0; k < NCHUNK; ++k) {
    C0[(size_t)k * NCH + ch] = c;
    c = P[(size_t)k * NCH + ch] * c + S[(size_t)k * NCH + ch];
  }
}

// ------- pass 2 (layer 1): h1 = r*c + (1-r)*x, written DIRECTLY swizzled ----
// IN-PLACE: h1 overwrites xsw.  Block = (h-slab 128, chunk of 32 t), 512 blocks.
#define TPAD 4112
__global__ __launch_bounds__(256) void scan1_pass2_fused(
    const unsigned short* __restrict__ Xt, const unsigned short* __restrict__ F,
    const unsigned short* __restrict__ R, unsigned short* __restrict__ xsw,
    const float* __restrict__ C0, unsigned short* __restrict__ h1last)
{
  __shared__ unsigned short st[4 * TPAD];
  const int hb = blockIdx.x;
  const int chunk = blockIdx.y;
  const int tid = threadIdx.x;
  const int b = tid >> 4, hg = tid & 15;
  const int h0 = hb * 128 + hg * 8;
  const int ch = b * 1024 + h0;
  const int tl   = hg >> 2;
  const int usub = (hg & 3) * 16 + b;

  float c[8];
  {
    const float4* C4 = (const float4*)&C0[(size_t)chunk * NCH + ch];
    float4 a = C4[0], d = C4[1];
    c[0]=a.x; c[1]=a.y; c[2]=a.z; c[3]=a.w; c[4]=d.x; c[5]=d.y; c[6]=d.z; c[7]=d.w;
  }

  size_t idx = (size_t)chunk * TCHUNK * NCH + ch;
  for (int t8 = 0; t8 < TCHUNK / 8; ++t8) {
#pragma unroll
    for (int ts = 0; ts < 8; ++ts) {
      const int t = chunk * TCHUNK + t8 * 8 + ts;
      ushort8_t fv = *(const ushort8_t*)&F[idx];
      ushort8_t xv = *(const ushort8_t*)&Xt[idx];
      ushort8_t rv = *(const ushort8_t*)&R[idx];
      const size_t soff = ((size_t)(t >> 3) * 32 + (h0 >> 5)) * 4096
                        + (size_t)(((t & 7) * 64 + usub) * 8);
      ushort8_t xo = *(const ushort8_t*)&xsw[soff];
      ushort8_t hv;
#pragma unroll
      for (int j = 0; j < 8; ++j) {
        float f  = bf16_to_f32(fv[j]);
        float xt = bf16_to_f32(xv[j]);
        c[j] = f * c[j] + (1.f - f) * xt;
        float r  = bf16_to_f32(rv[j]);
        float xval = bf16_to_f32(xo[j]);
        hv[j] = f32_to_bf16(r * c[j] + (1.f - r) * xval);
      }
      *(ushort8_t*)&st[tl * TPAD + (ts * 64 + usub) * 8] = hv;
      if (t == SEQ - 1) *(ushort8_t*)&h1last[ch] = hv;
      idx += NCH;
    }
    __syncthreads();
    const size_t gbase = (((size_t)chunk * (TCHUNK / 8) + t8) * 32 + hb * 4) * 4096;
#pragma unroll
    for (int tl2 = 0; tl2 < 4; ++tl2) {
      size_t gdst = gbase + (size_t)tl2 * 4096 + tid * 16;
      *(ushort8_t*)&xsw[gdst]     = *(const ushort8_t*)&st[tl2 * TPAD + tid * 16];
      *(ushort8_t*)&xsw[gdst + 8] = *(const ushort8_t*)&st[tl2 * TPAD + tid * 16 + 8];
    }
    __syncthreads();
  }
}

// ------- r2 at last timestep: (16x1024) @ W1[:,2048:3072] fp32, 64 blocks ---
__global__ __launch_bounds__(256) void r2_kernel(
    const unsigned short* __restrict__ h1last, const float* __restrict__ W1,
    const float* __restrict__ b1, float* __restrict__ r2) {
  __shared__ float xrow[1024];
  const int b = blockIdx.x, nq = blockIdx.y, tid = threadIdx.x;
  for (int i = tid; i < 1024; i += 256)
    xrow[i] = bf16_to_f32(h1last[b * 1024 + i]);
  __syncthreads();
  const int n = nq * 256 + tid;
  float acc = b1[1024 + n];
  for (int d = 0; d < 1024; ++d)
    acc += xrow[d] * W1[(size_t)d * 3072 + 2048 + n];
  r2[b * 1024 + n] = sigmoidf_(acc);
}

// ------- layer-2: 256-segment serial combine + output, 1 ch/thread ----------
// 64 blocks, coalesced 4 B loads.
__global__ __launch_bounds__(256) void final_l2(
    const float* __restrict__ Pseg, const float* __restrict__ Sseg,
    const float* __restrict__ r2, const unsigned short* __restrict__ h1last,
    float* __restrict__ out) {
  const int ch = blockIdx.x * 256 + threadIdx.x;
  float c = 0.f;
#pragma unroll 8
  for (int k = 0; k < NSEG; ++k)
    c = Pseg[(size_t)k * NCH + ch] * c + Sseg[(size_t)k * NCH + ch];
  float r = r2[ch];
  float x = bf16_to_f32(h1last[ch]);
  out[ch] = r * c + (1.f - r) * x;
}

extern "C" void kernel_launch(void* const* d_in, const int* in_sizes, int n_in,
                              void* d_out, int out_size, void* d_ws, size_t ws_size,
                              hipStream_t stream) {
  const float* x  = (const float*)d_in[0];
  const float* W0 = (const float*)d_in[1];
  const float* b0 = (const float*)d_in[2];
  const float* W1 = (const float*)d_in[3];
  const float* b1 = (const float*)d_in[4];
  float* out = (float*)d_out;

  char* ws = (char*)d_ws;
  auto alloc = [&](size_t bytes) {
    char* p = ws; ws += (bytes + 255) & ~(size_t)255; return p;
  };
  const size_t NE = (size_t)M_TOT * HID;
  unsigned short* xsw   = (unsigned short*)alloc(NE * 2);   // x swizzled; h1 in-place
  unsigned short* W0sw  = (unsigned short*)alloc((size_t)3072 * 1024 * 2);
  unsigned short* W1sw  = (unsigned short*)alloc((size_t)3072 * 1024 * 2);
  unsigned short* Xt    = (unsigned short*)alloc(NE * 2);
  unsigned short* F     = (unsigned short*)alloc(NE * 2);
  unsigned short* R     = (unsigned short*)alloc(NE * 2);
  unsigned short* h1last= (unsigned short*)alloc((size_t)NCH * 2);
  float* P    = (float*)alloc((size_t)NCHUNK * NCH * 4);
  float* S    = (float*)alloc((size_t)NCHUNK * NCH * 4);
  float* C0   = (float*)alloc((size_t)NCHUNK * NCH * 4);
  float* Pseg = (float*)alloc((size_t)NSEG * NCH * 4);      // 16.8 MB
  float* Sseg = (float*)alloc((size_t)NSEG * NCH * 4);
  float* r2   = (float*)alloc((size_t)NCH * 4);

  dim3 blk256(256);
  // 1. preprocessing: x->xsw, W0->W0sw, W1->W1sw
  prep_all<<<dim3(9728), blk256, 0, stream>>>(x, W0, W1, xsw, W0sw, W1sw);
  // 2. layer-1 GEMM (N=3072, BN=256 -> 12 bn blocks), direct-load
  gemm_direct<<<dim3(256 * 12), blk256, 0, stream>>>(xsw, W0sw, Xt, F, R, b0, 12);
  // 3. blocked scan layer 1 (64 chunks x 32 t)
  scan_pass1<<<dim3(8, NCHUNK), blk256, 0, stream>>>(Xt, F, P, S);
  combine_c0<<<dim3(NCH / 256), blk256, 0, stream>>>(P, S, C0);
  scan1_pass2_fused<<<dim3(8, NCHUNK), blk256, 0, stream>>>(Xt, F, R, xsw, C0, h1last);
  // 4. r2 at last timestep
  r2_kernel<<<dim3(16, 4), blk256, 0, stream>>>(h1last, W1, b1, r2);
  // 5. layer-2 GEMM with fused segment scan (writes only Pseg/Sseg)
  gemm2_scan<<<dim3(2048), blk256, 0, stream>>>(xsw, W1sw, b1, Pseg, Sseg);
  // 6. 256-segment combine + output (64 blocks, coalesced)
  final_l2<<<dim3(NCH / 256), blk256, 0, stream>>>(Pseg, Sseg, r2, h1last, out);
}